// Round 5
// baseline (6570.854 us; speedup 1.0000x reference)
//
#include <hip/hip_runtime.h>
#include <hip/hip_bf16.h>
#include <hip/hip_cooperative_groups.h>
#include <cmath>

namespace cg = cooperative_groups;

// ---------------------------------------------------------------------------
// Model dims: H=256 HID=128 V=50000 LV=200 N=512 L=64 M=64 C=4 T=8 K=8
// ---------------------------------------------------------------------------

__device__ __forceinline__ float sigf(float x) { return 1.f / (1.f + expf(-x)); }
__device__ __forceinline__ float b2f(__hip_bfloat16 x) { return __bfloat162float(x); }

// ---------------------------------------------------------------------------
// WXALL weights: [wiou (768) | wf (256)] rows x 256, bias [biou | bf]
// ---------------------------------------------------------------------------
__global__ __launch_bounds__(256) void k_build_wx(const float* __restrict__ wiou,
                                                  const float* __restrict__ wf,
                                                  const float* __restrict__ biou,
                                                  const float* __restrict__ bf,
                                                  float* __restrict__ w,
                                                  float* __restrict__ b) {
  int i = blockIdx.x * 256 + threadIdx.x;
  if (i < 1024 * 256) {
    int j = i >> 8, k = i & 255;
    w[i] = (j < 768) ? wiou[j * 256 + k] : wf[(j - 768) * 256 + k];
  }
  if (i < 1024) b[i] = (i < 768) ? biou[i] : bf[i - 768];
}

// WPROJ: [uiou (768) | uf (256)] rows x 256
__global__ __launch_bounds__(256) void k_build_wproj(const float* __restrict__ uiou,
                                                     const float* __restrict__ uf,
                                                     float* __restrict__ w) {
  int i = blockIdx.x * 256 + threadIdx.x;
  if (i >= 1024 * 256) return;
  int j = i >> 8, k = i & 255;
  w[i] = (j < 768) ? uiou[j * 256 + k] : uf[(j - 768) * 256 + k];
}

__global__ __launch_bounds__(256) void k_zero_misc(float* __restrict__ nei_sum,
                                                   int* __restrict__ deg,
                                                   int* __restrict__ flag) {
  int i = blockIdx.x * 256 + threadIdx.x;
  if (i < 512 * 256) nei_sum[i] = 0.f;
  if (i < 512) deg[i] = 0;
  if (i == 0) *flag = 0;
}

// bool-mask dtype detector (int32 vs byte-packed)
__global__ __launch_bounds__(256) void k_mask_detect(const unsigned* __restrict__ raw,
                                                     int* __restrict__ flag) {
  int i = blockIdx.x * 256 + threadIdx.x;
  if (i < 32768) {
    if (raw[i] > 1u) atomicOr(flag, 1);
  }
}

__global__ __launch_bounds__(256) void k_mask_convert(const void* __restrict__ raw,
                                                      const int* __restrict__ flag,
                                                      int* __restrict__ msk) {
  int i = blockIdx.x * 256 + threadIdx.x;
  if (i >= 512 * 64 * 4) return;
  int v;
  if (*flag) v = ((const unsigned char*)raw)[i] != 0;
  else       v = ((const int*)raw)[i] != 0;
  msk[i] = v;
}

// ---------------------------------------------------------------------------
// Generic fp32 GEMM: 128x128 tile, 256 threads, 8x8 micro as 2x2 quads of
// 4x4 (conflict-free LDS), K chunk 16. Optional bf16 output.
// ---------------------------------------------------------------------------
__global__ __launch_bounds__(256) void k_gemm128(const float* __restrict__ A,
                                                 const int* __restrict__ ridx,
                                                 int rstride,
                                                 const float* __restrict__ W,
                                                 const float* __restrict__ bias,
                                                 float* __restrict__ C,
                                                 int R, int K, int J, int relu,
                                                 int out_bf16) {
  __shared__ float As[16][132];
  __shared__ float Ws[16][132];
  int njt = J >> 7;
  int rt = blockIdx.x / njt;
  int jt = blockIdx.x % njt;
  int tid = threadIdx.x;
  int tx = tid & 15, ty = tid >> 4;

  int row2 = tid >> 1;
  int kq = (tid & 1) * 4;
  int gr = rt * 128 + row2;
  const float* arow = A + (size_t)(ridx ? ridx[gr] : gr) * rstride;
  const float* wrow = W + (size_t)(jt * 128 + row2) * K;

  float acc[8][8];
#pragma unroll
  for (int i = 0; i < 8; ++i)
#pragma unroll
    for (int j = 0; j < 8; ++j) acc[i][j] = 0.f;

  for (int k0 = 0; k0 < K; k0 += 16) {
    float4 av0 = *(const float4*)(arow + k0 + kq);
    float4 av1 = *(const float4*)(arow + k0 + kq + 8);
    float4 wv0 = *(const float4*)(wrow + k0 + kq);
    float4 wv1 = *(const float4*)(wrow + k0 + kq + 8);
    __syncthreads();
    As[kq + 0][row2] = av0.x; As[kq + 1][row2] = av0.y;
    As[kq + 2][row2] = av0.z; As[kq + 3][row2] = av0.w;
    As[kq + 8][row2] = av1.x; As[kq + 9][row2] = av1.y;
    As[kq + 10][row2] = av1.z; As[kq + 11][row2] = av1.w;
    Ws[kq + 0][row2] = wv0.x; Ws[kq + 1][row2] = wv0.y;
    Ws[kq + 2][row2] = wv0.z; Ws[kq + 3][row2] = wv0.w;
    Ws[kq + 8][row2] = wv1.x; Ws[kq + 9][row2] = wv1.y;
    Ws[kq + 10][row2] = wv1.z; Ws[kq + 11][row2] = wv1.w;
    __syncthreads();
#pragma unroll
    for (int kk = 0; kk < 16; ++kk) {
      float a[8], b[8];
      *(float4*)&a[0] = *(const float4*)&As[kk][ty * 4];
      *(float4*)&a[4] = *(const float4*)&As[kk][64 + ty * 4];
      *(float4*)&b[0] = *(const float4*)&Ws[kk][tx * 4];
      *(float4*)&b[4] = *(const float4*)&Ws[kk][64 + tx * 4];
#pragma unroll
      for (int i = 0; i < 8; ++i)
#pragma unroll
        for (int j = 0; j < 8; ++j) acc[i][j] += a[i] * b[j];
    }
  }

  int col0 = jt * 128 + tx * 4;
  int col1 = jt * 128 + 64 + tx * 4;
  float b0[4], b1[4];
#pragma unroll
  for (int j = 0; j < 4; ++j) {
    b0[j] = bias ? bias[col0 + j] : 0.f;
    b1[j] = bias ? bias[col1 + j] : 0.f;
  }
#pragma unroll
  for (int i = 0; i < 8; ++i) {
    int row = rt * 128 + ((i < 4) ? (ty * 4 + i) : (64 + ty * 4 + i - 4));
    float v0[4], v1[4];
#pragma unroll
    for (int j = 0; j < 4; ++j) {
      float x0 = acc[i][j] + b0[j];
      float x1 = acc[i][j + 4] + b1[j];
      if (relu) { x0 = fmaxf(x0, 0.f); x1 = fmaxf(x1, 0.f); }
      v0[j] = x0; v1[j] = x1;
    }
    if (out_bf16) {
      __hip_bfloat16* Cb = (__hip_bfloat16*)C;
      union { ushort4 u; __hip_bfloat16 b[4]; } p0, p1;
#pragma unroll
      for (int j = 0; j < 4; ++j) { p0.b[j] = __float2bfloat16(v0[j]); p1.b[j] = __float2bfloat16(v1[j]); }
      *(ushort4*)(Cb + (size_t)row * J + col0) = p0.u;
      *(ushort4*)(Cb + (size_t)row * J + col1) = p1.u;
    } else {
      *(float4*)(C + (size_t)row * J + col0) = *(float4*)v0;
      *(float4*)(C + (size_t)row * J + col1) = *(float4*)v1;
    }
  }
}

// ---------------------------------------------------------------------------
// GRU recurrence v3 (bf16 gi input)
// ---------------------------------------------------------------------------
__global__ __launch_bounds__(512, 2) void k_gru3(const __hip_bfloat16* __restrict__ gi,
                                                 const float* __restrict__ whh,
                                                 const float* __restrict__ bhh,
                                                 float* __restrict__ out,
                                                 int L) {
  __shared__ float hs[4][132];
  __shared__ float parts[4][8][388];
  int tid = threadIdx.x;
  int d = blockIdx.y;
  int n0 = blockIdx.x * 4;
  int ks = tid >> 6;
  int rg = tid & 63;
  int kb = ks * 16;
  const float* wbase = whh + (size_t)d * 384 * 128;

  float4 w4[6][4];
#pragma unroll
  for (int r = 0; r < 6; ++r) {
    const float* wr = wbase + (size_t)(r * 64 + rg) * 128 + kb;
#pragma unroll
    for (int q = 0; q < 4; ++q) w4[r][q] = ((const float4*)wr)[q];
  }

  int sg = tid >> 7, jg = tid & 127;
  const float* bh = bhh + d * 384;
  float br = bh[jg], bz = bh[128 + jg], bn = bh[256 + jg];

  for (int i = tid; i < 4 * 132; i += 512) ((float*)hs)[i] = 0.f;
  __syncthreads();

  int t = d ? (L - 1) : 0;
  int dt = d ? -1 : 1;

  for (int step = 0; step < L; ++step, t += dt) {
    const __hip_bfloat16* g = gi + (size_t)((n0 + sg) * L + t) * 768 + d * 384;
    float pgr = b2f(g[jg]), pgz = b2f(g[128 + jg]), pgn = b2f(g[256 + jg]);

    float acc[4][6];
#pragma unroll
    for (int s = 0; s < 4; ++s)
#pragma unroll
      for (int r = 0; r < 6; ++r) acc[s][r] = 0.f;
#pragma unroll
    for (int s = 0; s < 4; ++s) {
#pragma unroll
      for (int q = 0; q < 4; ++q) {
        float4 hv = *(const float4*)&hs[s][kb + q * 4];
#pragma unroll
        for (int r = 0; r < 6; ++r) {
          acc[s][r] += w4[r][q].x * hv.x + w4[r][q].y * hv.y +
                       w4[r][q].z * hv.z + w4[r][q].w * hv.w;
        }
      }
    }
#pragma unroll
    for (int s = 0; s < 4; ++s)
#pragma unroll
      for (int r = 0; r < 6; ++r) parts[s][ks][r * 64 + rg] = acc[s][r];
    __syncthreads();
    {
      float sr = 0.f, sz = 0.f, sn = 0.f;
#pragma unroll
      for (int k = 0; k < 8; ++k) {
        sr += parts[sg][k][jg];
        sz += parts[sg][k][128 + jg];
        sn += parts[sg][k][256 + jg];
      }
      float r = sigf(pgr + sr + br);
      float z = sigf(pgz + sz + bz);
      float nn = tanhf(pgn + r * (sn + bn));
      float hold = hs[sg][jg];
      float hnew = (1.f - z) * nn + z * hold;
      hs[sg][jg] = hnew;
      out[(size_t)((n0 + sg) * L + t) * 256 + d * 128 + jg] = hnew;
    }
    __syncthreads();
  }
}

// ---------------------------------------------------------------------------
// Attention pool (one block per n)
// ---------------------------------------------------------------------------
__global__ __launch_bounds__(256) void k_attn_pool(const float* __restrict__ score_src,
                                                   int s_ns, int s_ls,
                                                   const float* __restrict__ val_src,
                                                   int v_ns, int v_ls,
                                                   const float* __restrict__ w,
                                                   const float* __restrict__ bptr,
                                                   float* __restrict__ dst,
                                                   int dst_stride, int L) {
  __shared__ float wts[64];
  int n = blockIdx.x;
  int tid = threadIdx.x;
  if (tid < 64) {
    float a = -INFINITY;
    if (tid < L) {
      const float* row = score_src + (size_t)n * s_ns + (size_t)tid * s_ls;
      float s = bptr[0];
      for (int h = 0; h < 256; h += 4) {
        float4 v = *(const float4*)(row + h);
        float4 wv = *(const float4*)(w + h);
        s += v.x * wv.x + v.y * wv.y + v.z * wv.z + v.w * wv.w;
      }
      a = s;
    }
    float mx = a;
#pragma unroll
    for (int off = 32; off; off >>= 1) mx = fmaxf(mx, __shfl_xor(mx, off));
    float e = (tid < L) ? expf(a - mx) : 0.f;
    float ss = e;
#pragma unroll
    for (int off = 32; off; off >>= 1) ss += __shfl_xor(ss, off);
    if (tid < L) wts[tid] = e / ss;
  }
  __syncthreads();
  float acc = 0.f;
  for (int l = 0; l < L; ++l)
    acc += wts[l] * val_src[(size_t)n * v_ns + (size_t)l * v_ls + tid];
  dst[(size_t)n * dst_stride + tid] = acc;
}

// ---------------------------------------------------------------------------
// xn[n][m][h] = 0.5*label_tab[lbl][h] + (1/16)*sum_t tok_tab[id][h]
// ---------------------------------------------------------------------------
__global__ __launch_bounds__(256) void k_xn(const float* __restrict__ label_tab,
                                            const float* __restrict__ tok_tab,
                                            const int* __restrict__ lbl_ids,
                                            const int* __restrict__ tok_ids,
                                            float* __restrict__ xn) {
  int nm = blockIdx.x;
  int h = threadIdx.x;
  const int* tids = tok_ids + (size_t)nm * 8;
  float s = 0.f;
#pragma unroll
  for (int t = 0; t < 8; ++t) s += tok_tab[(size_t)tids[t] * 256 + h];
  xn[(size_t)nm * 256 + h] = 0.5f * label_tab[(size_t)lbl_ids[nm] * 256 + h] + 0.0625f * s;
}

// ---------------------------------------------------------------------------
// Fused TreeLSTM: 64 steps in one cooperative kernel.
//   grid 256 blocks x 512 threads.
//   Phase A (combine, step m): thread -> (n = blk*2 + tid>>8, h = tid&255):
//     gates from XWALL(bf16) + gathered HU(bf16) rows; writes h,c (fp32).
//   Phase B (proj): HU[m] = h_m @ WPROJ^T -> bf16. 256 tiles of 32x64, K=256.
// ---------------------------------------------------------------------------
__global__ __launch_bounds__(512) void k_tl_fused(__hip_bfloat16* __restrict__ HU,
                                                  const __hip_bfloat16* __restrict__ XWALL,
                                                  const float* __restrict__ WPROJ,
                                                  const int* __restrict__ ch,
                                                  const int* __restrict__ msk,
                                                  float* __restrict__ h_arr,
                                                  float* __restrict__ c_arr) {
  cg::grid_group grid = cg::this_grid();
  __shared__ float As[16][36];
  __shared__ float Ws[16][68];
  int tid = threadIdx.x;
  int blk = blockIdx.x;

  // phase A ids
  int an = blk * 2 + (tid >> 8);
  int ah = tid & 255;
  // phase B ids: tile rt (32 rows) x jt (64 cols)
  int rt = blk >> 4, jt = blk & 15;
  int ty = tid >> 4;          // 0..31 -> row in tile
  int tx = tid & 15;          // 0..15 -> col group of 4
  int sr = tid >> 4, skq = (tid & 15);  // A stage: not used directly below

  for (int m = 0; m < 64; ++m) {
    // ---- phase A: combine ----
    {
      int n = an, h = ah;
      const __hip_bfloat16* xw = XWALL + ((size_t)(n * 64 + m)) * 1024;
      float si = b2f(xw[h]), so = b2f(xw[256 + h]), su = b2f(xw[512 + h]);
      float xfv = b2f(xw[768 + h]);
      const int* chp = ch + ((size_t)(n * 64 + m)) * 4;
      const int* mkp = msk + ((size_t)(n * 64 + m)) * 4;
      float cs = 0.f;
#pragma unroll
      for (int c = 0; c < 4; ++c) {
        if (mkp[c]) {
          int cc = chp[c];
          const __hip_bfloat16* hu = HU + ((size_t)cc * 512 + n) * 1024;
          si += b2f(hu[h]);
          so += b2f(hu[256 + h]);
          su += b2f(hu[512 + h]);
          float fg = sigf(xfv + b2f(hu[768 + h]));
          cs += fg * c_arr[((size_t)cc * 512 + n) * 256 + h];
        }
      }
      float iv = sigf(si), ov = sigf(so), uv = tanhf(su);
      float cn = iv * uv + cs;
      float hn = ov * tanhf(cn);
      h_arr[((size_t)m * 512 + n) * 256 + h] = hn;
      c_arr[((size_t)m * 512 + n) * 256 + h] = cn;
    }
    if (m == 63) break;   // HU[63] never read
    grid.sync();

    // ---- phase B: proj HU[m] = h_m @ WPROJ^T ----
    {
      float acc[4] = {0.f, 0.f, 0.f, 0.f};
      // staging maps
      int arow = tid >> 4;            // 0..31
      int ak = (tid & 15);            // 16 k-slots? we load 1 float each (16 k per chunk)
      int wrow = tid >> 3;            // 0..63
      int wk = (tid & 7) * 2;         // float2 per thread
      const float* hbase = h_arr + (size_t)(m * 512 + rt * 32) * 256;
      const float* wbase = WPROJ + (size_t)(jt * 64) * 256;
      for (int k0 = 0; k0 < 256; k0 += 16) {
        float av = hbase[(size_t)arow * 256 + k0 + ak];
        float2 wv = *(const float2*)(wbase + (size_t)wrow * 256 + k0 + wk);
        __syncthreads();
        As[ak][arow] = av;
        Ws[wk][wrow] = wv.x;
        Ws[wk + 1][wrow] = wv.y;
        __syncthreads();
#pragma unroll
        for (int kk = 0; kk < 16; ++kk) {
          float a = As[kk][ty];
          float4 bv = *(const float4*)&Ws[kk][tx * 4];
          acc[0] += a * bv.x; acc[1] += a * bv.y;
          acc[2] += a * bv.z; acc[3] += a * bv.w;
        }
      }
      union { ushort4 u; __hip_bfloat16 b[4]; } p;
#pragma unroll
      for (int j = 0; j < 4; ++j) p.b[j] = __float2bfloat16(acc[j]);
      __hip_bfloat16* outp = HU + (size_t)m * 512 * 1024 +
                             (size_t)(rt * 32 + ty) * 1024 + jt * 64 + tx * 4;
      *(ushort4*)outp = p.u;
    }
    grid.sync();
  }
}

// ---------------------------------------------------------------------------
// Graph kernels
// ---------------------------------------------------------------------------
__global__ __launch_bounds__(256) void k_edge_deg(const int* __restrict__ edges,
                                                  int* __restrict__ deg, int E) {
  int i = blockIdx.x * 256 + threadIdx.x;
  if (i < E) {
    atomicAdd(&deg[edges[2 * i]], 1);
    atomicAdd(&deg[edges[2 * i + 1]], 1);
  }
}

__global__ __launch_bounds__(256) void k_nei(const int* __restrict__ edges,
                                             const float* __restrict__ x,
                                             float* __restrict__ nei_sum) {
  int e = blockIdx.x, h = threadIdx.x;
  int a = edges[2 * e], b = edges[2 * e + 1];
  atomicAdd(&nei_sum[(size_t)a * 256 + h], x[(size_t)b * 256 + h]);
  atomicAdd(&nei_sum[(size_t)b * 256 + h], x[(size_t)a * 256 + h]);
}

__global__ __launch_bounds__(256) void k_xcat(const float* __restrict__ x,
                                              const float* __restrict__ nei_sum,
                                              const int* __restrict__ deg,
                                              float* __restrict__ xcat) {
  int n = blockIdx.x, h = threadIdx.x;
  xcat[(size_t)n * 512 + h] = x[(size_t)n * 256 + h];
  float d = fmaxf((float)deg[n], 1.f);
  xcat[(size_t)n * 512 + 256 + h] = nei_sum[(size_t)n * 256 + h] / d;
}

__global__ __launch_bounds__(256) void k_spmm_self(const float* __restrict__ y,
                                                   const int* __restrict__ deg,
                                                   float* __restrict__ ob) {
  int n = blockIdx.x, h = threadIdx.x;
  float dis2 = 1.f / (float)(deg[n] + 1);
  ob[(size_t)n * 256 + h] = dis2 * y[(size_t)n * 256 + h];
}

__global__ __launch_bounds__(256) void k_spmm_edge(const float* __restrict__ y,
                                                   const int* __restrict__ deg,
                                                   const int* __restrict__ edges,
                                                   float* __restrict__ ob) {
  int e = blockIdx.x, h = threadIdx.x;
  int a = edges[2 * e], b = edges[2 * e + 1];
  float w = (1.f / sqrtf((float)(deg[a] + 1))) * (1.f / sqrtf((float)(deg[b] + 1)));
  atomicAdd(&ob[(size_t)a * 256 + h], w * y[(size_t)b * 256 + h]);
  atomicAdd(&ob[(size_t)b * 256 + h], w * y[(size_t)a * 256 + h]);
}

__global__ __launch_bounds__(256) void k_relu_inplace(float* __restrict__ p) {
  int i = blockIdx.x * 256 + threadIdx.x;
  p[i] = fmaxf(p[i], 0.f);
}

__global__ __launch_bounds__(256) void k_final(const float* __restrict__ h2,
                                               const float* __restrict__ w1,
                                               const float* __restrict__ b1,
                                               const float* __restrict__ w2,
                                               const float* __restrict__ b2,
                                               float* __restrict__ outp) {
  __shared__ float gv[512];
  __shared__ float zz[256];
  int tid = threadIdx.x;
  float mn = 0.f, mx = -INFINITY;
  for (int n = 0; n < 512; ++n) {
    float v = h2[(size_t)n * 256 + tid];
    mn += v;
    mx = fmaxf(mx, v);
  }
  gv[tid] = mn / 512.f;
  gv[256 + tid] = mx;
  __syncthreads();
  float acc = b1[tid];
  for (int k = 0; k < 512; ++k) acc += gv[k] * w1[(size_t)tid * 512 + k];
  zz[tid] = fmaxf(acc, 0.f) * w2[tid];
  __syncthreads();
  for (int s = 128; s; s >>= 1) {
    if (tid < s) zz[tid] += zz[tid + s];
    __syncthreads();
  }
  if (tid == 0) outp[0] = zz[0] + b2[0];
}

// ---------------------------------------------------------------------------
// Host launch
// ---------------------------------------------------------------------------
extern "C" void kernel_launch(void* const* d_in, const int* in_sizes, int n_in,
                              void* d_out, int out_size, void* d_ws, size_t ws_size,
                              hipStream_t stream) {
  const int* seq_tokens    = (const int*)d_in[0];
  const int* ast_children  = (const int*)d_in[1];
  const void* ast_mask_raw = (const void*)d_in[2];
  const int* ast_label_ids = (const int*)d_in[3];
  const int* ast_tok_ids   = (const int*)d_in[4];
  const int* ctx_nei       = (const int*)d_in[5];
  const int* edges         = (const int*)d_in[6];
  const float* seq_emb  = (const float*)d_in[7];
  const float* seq_wih  = (const float*)d_in[8];
  const float* seq_whh  = (const float*)d_in[9];
  const float* seq_bih  = (const float*)d_in[10];
  const float* seq_bhh  = (const float*)d_in[11];
  const float* seq_pw   = (const float*)d_in[12];
  const float* seq_pb   = (const float*)d_in[13];
  const float* ctx_wih  = (const float*)d_in[14];
  const float* ctx_whh  = (const float*)d_in[15];
  const float* ctx_bih  = (const float*)d_in[16];
  const float* ctx_bhh  = (const float*)d_in[17];
  const float* ctx_pw   = (const float*)d_in[18];
  const float* ctx_pb   = (const float*)d_in[19];
  const float* ast_label_tab = (const float*)d_in[20];
  const float* ast_tok_tab   = (const float*)d_in[21];
  const float* ast_pw   = (const float*)d_in[22];
  const float* ast_pb   = (const float*)d_in[23];
  const float* tl_wiou  = (const float*)d_in[24];
  const float* tl_biou  = (const float*)d_in[25];
  const float* tl_uiou  = (const float*)d_in[26];
  const float* tl_wf    = (const float*)d_in[27];
  const float* tl_bf    = (const float*)d_in[28];
  const float* tl_uf    = (const float*)d_in[29];
  const float* fa_wih   = (const float*)d_in[30];
  const float* fa_whh   = (const float*)d_in[31];
  const float* fa_bih   = (const float*)d_in[32];
  const float* fa_bhh   = (const float*)d_in[33];
  const float* fa_aw    = (const float*)d_in[34];
  const float* fa_ab    = (const float*)d_in[35];
  const float* comb_w   = (const float*)d_in[36];
  const float* comb_b   = (const float*)d_in[37];
  const float* g1_w     = (const float*)d_in[38];
  const float* g1_b     = (const float*)d_in[39];
  const float* g2_w     = (const float*)d_in[40];
  const float* g2_b     = (const float*)d_in[41];
  const float* cls_w1   = (const float*)d_in[42];
  const float* cls_b1   = (const float*)d_in[43];
  const float* cls_w2   = (const float*)d_in[44];
  const float* cls_b2   = (const float*)d_in[45];
  float* outp = (float*)d_out;
  float* ws = (float*)d_ws;
  int E = in_sizes[6] / 2;

  // ----- workspace layout (floats) -----
  size_t off = 0;
  auto take = [&](size_t n) { size_t o = off; off += n; return o; };
  const size_t F_FEATS = take(512 * 5 * 256);
  const size_t F_X     = take(512 * 256);
  const size_t F_X2    = take(512 * 256);
  const size_t F_Y     = take(512 * 256);
  const size_t F_H1    = take(512 * 256);
  const size_t F_H2    = take(512 * 256);
  const size_t F_XCAT  = take(512 * 512);
  const size_t F_NEI   = take(512 * 256);
  const size_t F_DEG   = take(512);
  const size_t F_FLAG  = take(16);
  const size_t F_MSK   = take(512 * 64 * 4);
  const size_t F_WXW   = take(1024 * 256);
  const size_t F_WXB   = take(1024);
  const size_t F_WPROJ = take(1024 * 256);
  const size_t F_REGION = take(83886080);  // shared phase region
  (void)ws_size;

  float* FEATS = ws + F_FEATS;
  float* X     = ws + F_X;
  float* X2    = ws + F_X2;
  float* Y     = ws + F_Y;
  float* H1    = ws + F_H1;
  float* H2    = ws + F_H2;
  float* XCAT  = ws + F_XCAT;
  float* NEI   = ws + F_NEI;
  int*   DEG   = (int*)(ws + F_DEG);
  int*   FLAG  = (int*)(ws + F_FLAG);
  int*   MSK   = (int*)(ws + F_MSK);
  float* WXW   = ws + F_WXW;
  float* WXB   = ws + F_WXB;
  float* WPROJ = ws + F_WPROJ;
  float* REG   = ws + F_REGION;
  // enc/ctx phase
  __hip_bfloat16* GI16  = (__hip_bfloat16*)REG;             // 32768x768 bf16 (12.6M floats)
  float* OUT   = REG + 13631488;                            // 8.39M fp32
  // TL phase
  __hip_bfloat16* XWALL16 = (__hip_bfloat16*)REG;           // 32768x1024 bf16 (16.8M floats)
  float* HARR  = REG + 17000000;                            // 8.39M
  float* CARR  = REG + 25500000;                            // 8.39M
  __hip_bfloat16* HU16 = (__hip_bfloat16*)(REG + 34000000); // 64x512x1024 bf16 (16.8M floats)
  float* XN    = REG + 51000000;                            // 8.39M
  // fa phase
  __hip_bfloat16* GIFA16 = (__hip_bfloat16*)REG;            // 2560x768 bf16
  float* OUTFA = REG + 1966080;

  auto gemm = [&](const float* A, const int* ridx, int rstride, const float* W,
                  const float* bias, float* C, int R, int K, int J, int relu,
                  int obf) {
    dim3 g((R / 128) * (J / 128));
    k_gemm128<<<g, 256, 0, stream>>>(A, ridx, rstride, W, bias, C, R, K, J, relu, obf);
  };

  // ---- prep ----
  k_build_wx<<<1024, 256, 0, stream>>>(tl_wiou, tl_wf, tl_biou, tl_bf, WXW, WXB);
  k_build_wproj<<<1024, 256, 0, stream>>>(tl_uiou, tl_uf, WPROJ);
  k_zero_misc<<<512, 256, 0, stream>>>(NEI, DEG, FLAG);
  k_mask_detect<<<128, 256, 0, stream>>>((const unsigned*)ast_mask_raw, FLAG);
  k_mask_convert<<<512, 256, 0, stream>>>(ast_mask_raw, FLAG, MSK);

  // ---- 3 sequence encoders: slots 0 (stmt), 2 (varn), 3 (vart) ----
  const int slot_of[3] = {0, 2, 3};
  for (int e = 0; e < 3; ++e) {
    gemm(seq_emb + (size_t)e * 50000 * 256, seq_tokens + (size_t)e * 32768, 256,
         seq_wih + (size_t)e * 768 * 256, seq_bih + (size_t)e * 768, (float*)GI16,
         32768, 256, 768, 0, 1);
    k_gru3<<<dim3(128, 2), 512, 0, stream>>>(GI16, seq_whh + (size_t)e * 2 * 384 * 128,
                                             seq_bhh + (size_t)e * 768, OUT, 64);
    k_attn_pool<<<512, 256, 0, stream>>>(OUT, 64 * 256, 256, OUT, 64 * 256, 256,
                                         seq_pw + e * 256, seq_pb + e,
                                         FEATS + slot_of[e] * 256, 1280, 64);
  }

  // ---- ctx encoder (needs stmt slot0): slot 4 ----
  gemm(FEATS, ctx_nei, 1280, ctx_wih, ctx_bih, (float*)GI16, 4096, 256, 768, 0, 1);
  k_gru3<<<dim3(128, 2), 512, 0, stream>>>(GI16, ctx_whh, ctx_bhh, OUT, 8);
  k_attn_pool<<<512, 256, 0, stream>>>(OUT, 8 * 256, 256, OUT, 8 * 256, 256,
                                       ctx_pw, ctx_pb, FEATS + 4 * 256, 1280, 8);

  // ---- AST TreeLSTM: slot 1 ----
  k_xn<<<32768, 256, 0, stream>>>(ast_label_tab, ast_tok_tab, ast_label_ids,
                                  ast_tok_ids, XN);
  gemm(XN, nullptr, 256, WXW, WXB, (float*)XWALL16, 32768, 256, 1024, 0, 1);
  {
    void* args[] = {(void*)&HU16, (void*)&XWALL16, (void*)&WPROJ,
                    (void*)&ast_children, (void*)&MSK, (void*)&HARR, (void*)&CARR};
    hipLaunchCooperativeKernel((const void*)k_tl_fused, dim3(256), dim3(512),
                               args, 0, stream);
  }
  k_attn_pool<<<512, 256, 0, stream>>>(HARR, 256, 512 * 256, HARR, 256, 512 * 256,
                                       ast_pw, ast_pb, FEATS + 1 * 256, 1280, 64);

  // ---- feature-attention biGRU over the 5 slots -> x ----
  gemm(FEATS, nullptr, 256, fa_wih, fa_bih, (float*)GIFA16, 2560, 256, 768, 0, 1);
  k_gru3<<<dim3(128, 2), 512, 0, stream>>>(GIFA16, fa_whh, fa_bhh, OUTFA, 5);
  k_attn_pool<<<512, 256, 0, stream>>>(OUTFA, 5 * 256, 256, FEATS, 1280, 256,
                                       fa_aw, fa_ab, X, 256, 5);

  // ---- graph section ----
  k_edge_deg<<<(E + 255) / 256, 256, 0, stream>>>(edges, DEG, E);
  k_nei<<<E, 256, 0, stream>>>(edges, X, NEI);
  k_xcat<<<512, 256, 0, stream>>>(X, NEI, DEG, XCAT);
  gemm(XCAT, nullptr, 512, comb_w, comb_b, X2, 512, 512, 256, 1, 0);
  gemm(X2, nullptr, 256, g1_w, g1_b, Y, 512, 256, 256, 0, 0);
  k_spmm_self<<<512, 256, 0, stream>>>(Y, DEG, H1);
  k_spmm_edge<<<E, 256, 0, stream>>>(Y, DEG, edges, H1);
  k_relu_inplace<<<512, 256, 0, stream>>>(H1);
  gemm(H1, nullptr, 256, g2_w, g2_b, Y, 512, 256, 256, 0, 0);
  k_spmm_self<<<512, 256, 0, stream>>>(Y, DEG, H2);
  k_spmm_edge<<<E, 256, 0, stream>>>(Y, DEG, edges, H2);
  k_relu_inplace<<<512, 256, 0, stream>>>(H2);
  k_final<<<1, 256, 0, stream>>>(H2, cls_w1, cls_b1, cls_w2, cls_b2, outp);
}

// Round 6
// 2905.340 us; speedup vs baseline: 2.2616x; 2.2616x over previous
//
#include <hip/hip_runtime.h>
#include <hip/hip_bf16.h>
#include <cmath>

// ---------------------------------------------------------------------------
// Model dims: H=256 HID=128 V=50000 LV=200 N=512 L=64 M=64 C=4 T=8 K=8
// NOTE (round 5 lesson): cooperative grid.sync() costs ~37us on MI355X —
// never use it for a 126-sync loop; per-step kernel launches (~2-3us) win.
// ---------------------------------------------------------------------------

__device__ __forceinline__ float sigf(float x) { return 1.f / (1.f + expf(-x)); }
__device__ __forceinline__ float b2f(__hip_bfloat16 x) { return __bfloat162float(x); }

// ---------------------------------------------------------------------------
// WXALL weights: [wiou (768) | wf (256)] rows x 256, bias [biou | bf]
// ---------------------------------------------------------------------------
__global__ __launch_bounds__(256) void k_build_wx(const float* __restrict__ wiou,
                                                  const float* __restrict__ wf,
                                                  const float* __restrict__ biou,
                                                  const float* __restrict__ bf,
                                                  float* __restrict__ w,
                                                  float* __restrict__ b) {
  int i = blockIdx.x * 256 + threadIdx.x;
  if (i < 1024 * 256) {
    int j = i >> 8, k = i & 255;
    w[i] = (j < 768) ? wiou[j * 256 + k] : wf[(j - 768) * 256 + k];
  }
  if (i < 1024) b[i] = (i < 768) ? biou[i] : bf[i - 768];
}

// WPROJ: [uiou (768) | uf (256)] rows x 256
__global__ __launch_bounds__(256) void k_build_wproj(const float* __restrict__ uiou,
                                                     const float* __restrict__ uf,
                                                     float* __restrict__ w) {
  int i = blockIdx.x * 256 + threadIdx.x;
  if (i >= 1024 * 256) return;
  int j = i >> 8, k = i & 255;
  w[i] = (j < 768) ? uiou[j * 256 + k] : uf[(j - 768) * 256 + k];
}

__global__ __launch_bounds__(256) void k_zero_misc(float* __restrict__ nei_sum,
                                                   int* __restrict__ deg,
                                                   int* __restrict__ flag) {
  int i = blockIdx.x * 256 + threadIdx.x;
  if (i < 512 * 256) nei_sum[i] = 0.f;
  if (i < 512) deg[i] = 0;
  if (i == 0) *flag = 0;
}

// bool-mask dtype detector (int32 vs byte-packed)
__global__ __launch_bounds__(256) void k_mask_detect(const unsigned* __restrict__ raw,
                                                     int* __restrict__ flag) {
  int i = blockIdx.x * 256 + threadIdx.x;
  if (i < 32768) {
    if (raw[i] > 1u) atomicOr(flag, 1);
  }
}

__global__ __launch_bounds__(256) void k_mask_convert(const void* __restrict__ raw,
                                                      const int* __restrict__ flag,
                                                      int* __restrict__ msk) {
  int i = blockIdx.x * 256 + threadIdx.x;
  if (i >= 512 * 64 * 4) return;
  int v;
  if (*flag) v = ((const unsigned char*)raw)[i] != 0;
  else       v = ((const int*)raw)[i] != 0;
  msk[i] = v;
}

// ---------------------------------------------------------------------------
// Generic fp32 GEMM: 128x128 tile, 256 threads, 8x8 micro as 2x2 quads of
// 4x4 (conflict-free LDS), K chunk 16. Optional bf16 output.
// ---------------------------------------------------------------------------
__global__ __launch_bounds__(256) void k_gemm128(const float* __restrict__ A,
                                                 const int* __restrict__ ridx,
                                                 int rstride,
                                                 const float* __restrict__ W,
                                                 const float* __restrict__ bias,
                                                 float* __restrict__ C,
                                                 int R, int K, int J, int relu,
                                                 int out_bf16) {
  __shared__ float As[16][132];
  __shared__ float Ws[16][132];
  int njt = J >> 7;
  int rt = blockIdx.x / njt;
  int jt = blockIdx.x % njt;
  int tid = threadIdx.x;
  int tx = tid & 15, ty = tid >> 4;

  int row2 = tid >> 1;
  int kq = (tid & 1) * 4;
  int gr = rt * 128 + row2;
  const float* arow = A + (size_t)(ridx ? ridx[gr] : gr) * rstride;
  const float* wrow = W + (size_t)(jt * 128 + row2) * K;

  float acc[8][8];
#pragma unroll
  for (int i = 0; i < 8; ++i)
#pragma unroll
    for (int j = 0; j < 8; ++j) acc[i][j] = 0.f;

  for (int k0 = 0; k0 < K; k0 += 16) {
    float4 av0 = *(const float4*)(arow + k0 + kq);
    float4 av1 = *(const float4*)(arow + k0 + kq + 8);
    float4 wv0 = *(const float4*)(wrow + k0 + kq);
    float4 wv1 = *(const float4*)(wrow + k0 + kq + 8);
    __syncthreads();
    As[kq + 0][row2] = av0.x; As[kq + 1][row2] = av0.y;
    As[kq + 2][row2] = av0.z; As[kq + 3][row2] = av0.w;
    As[kq + 8][row2] = av1.x; As[kq + 9][row2] = av1.y;
    As[kq + 10][row2] = av1.z; As[kq + 11][row2] = av1.w;
    Ws[kq + 0][row2] = wv0.x; Ws[kq + 1][row2] = wv0.y;
    Ws[kq + 2][row2] = wv0.z; Ws[kq + 3][row2] = wv0.w;
    Ws[kq + 8][row2] = wv1.x; Ws[kq + 9][row2] = wv1.y;
    Ws[kq + 10][row2] = wv1.z; Ws[kq + 11][row2] = wv1.w;
    __syncthreads();
#pragma unroll
    for (int kk = 0; kk < 16; ++kk) {
      float a[8], b[8];
      *(float4*)&a[0] = *(const float4*)&As[kk][ty * 4];
      *(float4*)&a[4] = *(const float4*)&As[kk][64 + ty * 4];
      *(float4*)&b[0] = *(const float4*)&Ws[kk][tx * 4];
      *(float4*)&b[4] = *(const float4*)&Ws[kk][64 + tx * 4];
#pragma unroll
      for (int i = 0; i < 8; ++i)
#pragma unroll
        for (int j = 0; j < 8; ++j) acc[i][j] += a[i] * b[j];
    }
  }

  int col0 = jt * 128 + tx * 4;
  int col1 = jt * 128 + 64 + tx * 4;
  float b0[4], b1[4];
#pragma unroll
  for (int j = 0; j < 4; ++j) {
    b0[j] = bias ? bias[col0 + j] : 0.f;
    b1[j] = bias ? bias[col1 + j] : 0.f;
  }
#pragma unroll
  for (int i = 0; i < 8; ++i) {
    int row = rt * 128 + ((i < 4) ? (ty * 4 + i) : (64 + ty * 4 + i - 4));
    float v0[4], v1[4];
#pragma unroll
    for (int j = 0; j < 4; ++j) {
      float x0 = acc[i][j] + b0[j];
      float x1 = acc[i][j + 4] + b1[j];
      if (relu) { x0 = fmaxf(x0, 0.f); x1 = fmaxf(x1, 0.f); }
      v0[j] = x0; v1[j] = x1;
    }
    if (out_bf16) {
      __hip_bfloat16* Cb = (__hip_bfloat16*)C;
      union { ushort4 u; __hip_bfloat16 b[4]; } p0, p1;
#pragma unroll
      for (int j = 0; j < 4; ++j) { p0.b[j] = __float2bfloat16(v0[j]); p1.b[j] = __float2bfloat16(v1[j]); }
      *(ushort4*)(Cb + (size_t)row * J + col0) = p0.u;
      *(ushort4*)(Cb + (size_t)row * J + col1) = p1.u;
    } else {
      *(float4*)(C + (size_t)row * J + col0) = *(float4*)v0;
      *(float4*)(C + (size_t)row * J + col1) = *(float4*)v1;
    }
  }
}

// ---------------------------------------------------------------------------
// GRU recurrence v3 (bf16 gi input)
// ---------------------------------------------------------------------------
__global__ __launch_bounds__(512, 2) void k_gru3(const __hip_bfloat16* __restrict__ gi,
                                                 const float* __restrict__ whh,
                                                 const float* __restrict__ bhh,
                                                 float* __restrict__ out,
                                                 int L) {
  __shared__ float hs[4][132];
  __shared__ float parts[4][8][388];
  int tid = threadIdx.x;
  int d = blockIdx.y;
  int n0 = blockIdx.x * 4;
  int ks = tid >> 6;
  int rg = tid & 63;
  int kb = ks * 16;
  const float* wbase = whh + (size_t)d * 384 * 128;

  float4 w4[6][4];
#pragma unroll
  for (int r = 0; r < 6; ++r) {
    const float* wr = wbase + (size_t)(r * 64 + rg) * 128 + kb;
#pragma unroll
    for (int q = 0; q < 4; ++q) w4[r][q] = ((const float4*)wr)[q];
  }

  int sg = tid >> 7, jg = tid & 127;
  const float* bh = bhh + d * 384;
  float br = bh[jg], bz = bh[128 + jg], bn = bh[256 + jg];

  for (int i = tid; i < 4 * 132; i += 512) ((float*)hs)[i] = 0.f;
  __syncthreads();

  int t = d ? (L - 1) : 0;
  int dt = d ? -1 : 1;

  for (int step = 0; step < L; ++step, t += dt) {
    const __hip_bfloat16* g = gi + (size_t)((n0 + sg) * L + t) * 768 + d * 384;
    float pgr = b2f(g[jg]), pgz = b2f(g[128 + jg]), pgn = b2f(g[256 + jg]);

    float acc[4][6];
#pragma unroll
    for (int s = 0; s < 4; ++s)
#pragma unroll
      for (int r = 0; r < 6; ++r) acc[s][r] = 0.f;
#pragma unroll
    for (int s = 0; s < 4; ++s) {
#pragma unroll
      for (int q = 0; q < 4; ++q) {
        float4 hv = *(const float4*)&hs[s][kb + q * 4];
#pragma unroll
        for (int r = 0; r < 6; ++r) {
          acc[s][r] += w4[r][q].x * hv.x + w4[r][q].y * hv.y +
                       w4[r][q].z * hv.z + w4[r][q].w * hv.w;
        }
      }
    }
#pragma unroll
    for (int s = 0; s < 4; ++s)
#pragma unroll
      for (int r = 0; r < 6; ++r) parts[s][ks][r * 64 + rg] = acc[s][r];
    __syncthreads();
    {
      float sr = 0.f, sz = 0.f, sn = 0.f;
#pragma unroll
      for (int k = 0; k < 8; ++k) {
        sr += parts[sg][k][jg];
        sz += parts[sg][k][128 + jg];
        sn += parts[sg][k][256 + jg];
      }
      float r = sigf(pgr + sr + br);
      float z = sigf(pgz + sz + bz);
      float nn = tanhf(pgn + r * (sn + bn));
      float hold = hs[sg][jg];
      float hnew = (1.f - z) * nn + z * hold;
      hs[sg][jg] = hnew;
      out[(size_t)((n0 + sg) * L + t) * 256 + d * 128 + jg] = hnew;
    }
    __syncthreads();
  }
}

// ---------------------------------------------------------------------------
// Attention pool (one block per n)
// ---------------------------------------------------------------------------
__global__ __launch_bounds__(256) void k_attn_pool(const float* __restrict__ score_src,
                                                   int s_ns, int s_ls,
                                                   const float* __restrict__ val_src,
                                                   int v_ns, int v_ls,
                                                   const float* __restrict__ w,
                                                   const float* __restrict__ bptr,
                                                   float* __restrict__ dst,
                                                   int dst_stride, int L) {
  __shared__ float wts[64];
  int n = blockIdx.x;
  int tid = threadIdx.x;
  if (tid < 64) {
    float a = -INFINITY;
    if (tid < L) {
      const float* row = score_src + (size_t)n * s_ns + (size_t)tid * s_ls;
      float s = bptr[0];
      for (int h = 0; h < 256; h += 4) {
        float4 v = *(const float4*)(row + h);
        float4 wv = *(const float4*)(w + h);
        s += v.x * wv.x + v.y * wv.y + v.z * wv.z + v.w * wv.w;
      }
      a = s;
    }
    float mx = a;
#pragma unroll
    for (int off = 32; off; off >>= 1) mx = fmaxf(mx, __shfl_xor(mx, off));
    float e = (tid < L) ? expf(a - mx) : 0.f;
    float ss = e;
#pragma unroll
    for (int off = 32; off; off >>= 1) ss += __shfl_xor(ss, off);
    if (tid < L) wts[tid] = e / ss;
  }
  __syncthreads();
  float acc = 0.f;
  for (int l = 0; l < L; ++l)
    acc += wts[l] * val_src[(size_t)n * v_ns + (size_t)l * v_ls + tid];
  dst[(size_t)n * dst_stride + tid] = acc;
}

// ---------------------------------------------------------------------------
// xn[n][m][h] = 0.5*label_tab[lbl][h] + (1/16)*sum_t tok_tab[id][h]
// ---------------------------------------------------------------------------
__global__ __launch_bounds__(256) void k_xn(const float* __restrict__ label_tab,
                                            const float* __restrict__ tok_tab,
                                            const int* __restrict__ lbl_ids,
                                            const int* __restrict__ tok_ids,
                                            float* __restrict__ xn) {
  int nm = blockIdx.x;
  int h = threadIdx.x;
  const int* tids = tok_ids + (size_t)nm * 8;
  float s = 0.f;
#pragma unroll
  for (int t = 0; t < 8; ++t) s += tok_tab[(size_t)tids[t] * 256 + h];
  xn[(size_t)nm * 256 + h] = 0.5f * label_tab[(size_t)lbl_ids[nm] * 256 + h] + 0.0625f * s;
}

// ---------------------------------------------------------------------------
// TreeLSTM combine (step m): gates from bf16 XWALL + gathered bf16 HU.
// ---------------------------------------------------------------------------
__global__ __launch_bounds__(256) void k_tl_combine4(const __hip_bfloat16* __restrict__ HU,
                                                     const __hip_bfloat16* __restrict__ XWALL,
                                                     const int* __restrict__ ch,
                                                     const int* __restrict__ msk,
                                                     float* __restrict__ h_arr,
                                                     float* __restrict__ c_arr,
                                                     int m) {
  int n = blockIdx.x, h = threadIdx.x;
  const __hip_bfloat16* xw = XWALL + ((size_t)(n * 64 + m)) * 1024;
  float si = b2f(xw[h]), so = b2f(xw[256 + h]), su = b2f(xw[512 + h]);
  float xfv = b2f(xw[768 + h]);
  const int* chp = ch + ((size_t)(n * 64 + m)) * 4;
  const int* mkp = msk + ((size_t)(n * 64 + m)) * 4;
  float cs = 0.f;
#pragma unroll
  for (int c = 0; c < 4; ++c) {
    if (mkp[c]) {
      int cc = chp[c];
      const __hip_bfloat16* hu = HU + ((size_t)cc * 512 + n) * 1024;
      si += b2f(hu[h]);
      so += b2f(hu[256 + h]);
      su += b2f(hu[512 + h]);
      float fg = sigf(xfv + b2f(hu[768 + h]));
      cs += fg * c_arr[((size_t)cc * 512 + n) * 256 + h];
    }
  }
  float iv = sigf(si), ov = sigf(so), uv = tanhf(su);
  float cn = iv * uv + cs;
  float hn = ov * tanhf(cn);
  h_arr[((size_t)m * 512 + n) * 256 + h] = hn;
  c_arr[((size_t)m * 512 + n) * 256 + h] = cn;
}

// ---------------------------------------------------------------------------
// TreeLSTM projection (step m): HU[m] = h_m @ WPROJ^T  (512x1024, K=256),
//   bf16 output. 64x64 tiles, 128 blocks, 4x4 micro, K chunk 16.
// ---------------------------------------------------------------------------
__global__ __launch_bounds__(256) void k_tl_proj(const float* __restrict__ h_arr,
                                                 const float* __restrict__ WPROJ,
                                                 __hip_bfloat16* __restrict__ HU,
                                                 int m) {
  __shared__ float As[16][68];
  __shared__ float Ws[16][68];
  int b = blockIdx.x;
  int rt = b >> 4, jt = b & 15;
  int tid = threadIdx.x;
  int tx = tid & 15, ty = tid >> 4;
  int row = tid >> 2;
  int kq = (tid & 3) * 4;

  const float* arow = h_arr + (size_t)(m * 512 + rt * 64 + row) * 256;
  const float* wrow = WPROJ + (size_t)(jt * 64 + row) * 256;

  float acc[4][4];
#pragma unroll
  for (int i = 0; i < 4; ++i)
#pragma unroll
    for (int j = 0; j < 4; ++j) acc[i][j] = 0.f;

  for (int k0 = 0; k0 < 256; k0 += 16) {
    float4 av = *(const float4*)(arow + k0 + kq);
    float4 wv = *(const float4*)(wrow + k0 + kq);
    __syncthreads();
    As[kq + 0][row] = av.x; As[kq + 1][row] = av.y;
    As[kq + 2][row] = av.z; As[kq + 3][row] = av.w;
    Ws[kq + 0][row] = wv.x; Ws[kq + 1][row] = wv.y;
    Ws[kq + 2][row] = wv.z; Ws[kq + 3][row] = wv.w;
    __syncthreads();
#pragma unroll
    for (int kk = 0; kk < 16; ++kk) {
      float a[4], bv[4];
      *(float4*)&a[0] = *(const float4*)&As[kk][ty * 4];
      *(float4*)&bv[0] = *(const float4*)&Ws[kk][tx * 4];
#pragma unroll
      for (int i = 0; i < 4; ++i)
#pragma unroll
        for (int j = 0; j < 4; ++j) acc[i][j] += a[i] * bv[j];
    }
  }

  __hip_bfloat16* outb = HU + (size_t)m * 512 * 1024;
#pragma unroll
  for (int i = 0; i < 4; ++i) {
    union { ushort4 u; __hip_bfloat16 b[4]; } p;
#pragma unroll
    for (int j = 0; j < 4; ++j) p.b[j] = __float2bfloat16(acc[i][j]);
    *(ushort4*)(outb + (size_t)(rt * 64 + ty * 4 + i) * 1024 + jt * 64 + tx * 4) = p.u;
  }
}

// ---------------------------------------------------------------------------
// Graph kernels
// ---------------------------------------------------------------------------
__global__ __launch_bounds__(256) void k_edge_deg(const int* __restrict__ edges,
                                                  int* __restrict__ deg, int E) {
  int i = blockIdx.x * 256 + threadIdx.x;
  if (i < E) {
    atomicAdd(&deg[edges[2 * i]], 1);
    atomicAdd(&deg[edges[2 * i + 1]], 1);
  }
}

__global__ __launch_bounds__(256) void k_nei(const int* __restrict__ edges,
                                             const float* __restrict__ x,
                                             float* __restrict__ nei_sum) {
  int e = blockIdx.x, h = threadIdx.x;
  int a = edges[2 * e], b = edges[2 * e + 1];
  atomicAdd(&nei_sum[(size_t)a * 256 + h], x[(size_t)b * 256 + h]);
  atomicAdd(&nei_sum[(size_t)b * 256 + h], x[(size_t)a * 256 + h]);
}

__global__ __launch_bounds__(256) void k_xcat(const float* __restrict__ x,
                                              const float* __restrict__ nei_sum,
                                              const int* __restrict__ deg,
                                              float* __restrict__ xcat) {
  int n = blockIdx.x, h = threadIdx.x;
  xcat[(size_t)n * 512 + h] = x[(size_t)n * 256 + h];
  float d = fmaxf((float)deg[n], 1.f);
  xcat[(size_t)n * 512 + 256 + h] = nei_sum[(size_t)n * 256 + h] / d;
}

__global__ __launch_bounds__(256) void k_spmm_self(const float* __restrict__ y,
                                                   const int* __restrict__ deg,
                                                   float* __restrict__ ob) {
  int n = blockIdx.x, h = threadIdx.x;
  float dis2 = 1.f / (float)(deg[n] + 1);
  ob[(size_t)n * 256 + h] = dis2 * y[(size_t)n * 256 + h];
}

__global__ __launch_bounds__(256) void k_spmm_edge(const float* __restrict__ y,
                                                   const int* __restrict__ deg,
                                                   const int* __restrict__ edges,
                                                   float* __restrict__ ob) {
  int e = blockIdx.x, h = threadIdx.x;
  int a = edges[2 * e], b = edges[2 * e + 1];
  float w = (1.f / sqrtf((float)(deg[a] + 1))) * (1.f / sqrtf((float)(deg[b] + 1)));
  atomicAdd(&ob[(size_t)a * 256 + h], w * y[(size_t)b * 256 + h]);
  atomicAdd(&ob[(size_t)b * 256 + h], w * y[(size_t)a * 256 + h]);
}

__global__ __launch_bounds__(256) void k_relu_inplace(float* __restrict__ p) {
  int i = blockIdx.x * 256 + threadIdx.x;
  p[i] = fmaxf(p[i], 0.f);
}

__global__ __launch_bounds__(256) void k_final(const float* __restrict__ h2,
                                               const float* __restrict__ w1,
                                               const float* __restrict__ b1,
                                               const float* __restrict__ w2,
                                               const float* __restrict__ b2,
                                               float* __restrict__ outp) {
  __shared__ float gv[512];
  __shared__ float zz[256];
  int tid = threadIdx.x;
  float mn = 0.f, mx = -INFINITY;
  for (int n = 0; n < 512; ++n) {
    float v = h2[(size_t)n * 256 + tid];
    mn += v;
    mx = fmaxf(mx, v);
  }
  gv[tid] = mn / 512.f;
  gv[256 + tid] = mx;
  __syncthreads();
  float acc = b1[tid];
  for (int k = 0; k < 512; ++k) acc += gv[k] * w1[(size_t)tid * 512 + k];
  zz[tid] = fmaxf(acc, 0.f) * w2[tid];
  __syncthreads();
  for (int s = 128; s; s >>= 1) {
    if (tid < s) zz[tid] += zz[tid + s];
    __syncthreads();
  }
  if (tid == 0) outp[0] = zz[0] + b2[0];
}

// ---------------------------------------------------------------------------
// Host launch
// ---------------------------------------------------------------------------
extern "C" void kernel_launch(void* const* d_in, const int* in_sizes, int n_in,
                              void* d_out, int out_size, void* d_ws, size_t ws_size,
                              hipStream_t stream) {
  const int* seq_tokens    = (const int*)d_in[0];
  const int* ast_children  = (const int*)d_in[1];
  const void* ast_mask_raw = (const void*)d_in[2];
  const int* ast_label_ids = (const int*)d_in[3];
  const int* ast_tok_ids   = (const int*)d_in[4];
  const int* ctx_nei       = (const int*)d_in[5];
  const int* edges         = (const int*)d_in[6];
  const float* seq_emb  = (const float*)d_in[7];
  const float* seq_wih  = (const float*)d_in[8];
  const float* seq_whh  = (const float*)d_in[9];
  const float* seq_bih  = (const float*)d_in[10];
  const float* seq_bhh  = (const float*)d_in[11];
  const float* seq_pw   = (const float*)d_in[12];
  const float* seq_pb   = (const float*)d_in[13];
  const float* ctx_wih  = (const float*)d_in[14];
  const float* ctx_whh  = (const float*)d_in[15];
  const float* ctx_bih  = (const float*)d_in[16];
  const float* ctx_bhh  = (const float*)d_in[17];
  const float* ctx_pw   = (const float*)d_in[18];
  const float* ctx_pb   = (const float*)d_in[19];
  const float* ast_label_tab = (const float*)d_in[20];
  const float* ast_tok_tab   = (const float*)d_in[21];
  const float* ast_pw   = (const float*)d_in[22];
  const float* ast_pb   = (const float*)d_in[23];
  const float* tl_wiou  = (const float*)d_in[24];
  const float* tl_biou  = (const float*)d_in[25];
  const float* tl_uiou  = (const float*)d_in[26];
  const float* tl_wf    = (const float*)d_in[27];
  const float* tl_bf    = (const float*)d_in[28];
  const float* tl_uf    = (const float*)d_in[29];
  const float* fa_wih   = (const float*)d_in[30];
  const float* fa_whh   = (const float*)d_in[31];
  const float* fa_bih   = (const float*)d_in[32];
  const float* fa_bhh   = (const float*)d_in[33];
  const float* fa_aw    = (const float*)d_in[34];
  const float* fa_ab    = (const float*)d_in[35];
  const float* comb_w   = (const float*)d_in[36];
  const float* comb_b   = (const float*)d_in[37];
  const float* g1_w     = (const float*)d_in[38];
  const float* g1_b     = (const float*)d_in[39];
  const float* g2_w     = (const float*)d_in[40];
  const float* g2_b     = (const float*)d_in[41];
  const float* cls_w1   = (const float*)d_in[42];
  const float* cls_b1   = (const float*)d_in[43];
  const float* cls_w2   = (const float*)d_in[44];
  const float* cls_b2   = (const float*)d_in[45];
  float* outp = (float*)d_out;
  float* ws = (float*)d_ws;
  int E = in_sizes[6] / 2;

  // ----- workspace layout (floats) -----
  size_t off = 0;
  auto take = [&](size_t n) { size_t o = off; off += n; return o; };
  const size_t F_FEATS = take(512 * 5 * 256);
  const size_t F_X     = take(512 * 256);
  const size_t F_X2    = take(512 * 256);
  const size_t F_Y     = take(512 * 256);
  const size_t F_H1    = take(512 * 256);
  const size_t F_H2    = take(512 * 256);
  const size_t F_XCAT  = take(512 * 512);
  const size_t F_NEI   = take(512 * 256);
  const size_t F_DEG   = take(512);
  const size_t F_FLAG  = take(16);
  const size_t F_MSK   = take(512 * 64 * 4);
  const size_t F_WXW   = take(1024 * 256);
  const size_t F_WXB   = take(1024);
  const size_t F_WPROJ = take(1024 * 256);
  const size_t F_REGION = take(83886080);  // shared phase region
  (void)ws_size;

  float* FEATS = ws + F_FEATS;
  float* X     = ws + F_X;
  float* X2    = ws + F_X2;
  float* Y     = ws + F_Y;
  float* H1    = ws + F_H1;
  float* H2    = ws + F_H2;
  float* XCAT  = ws + F_XCAT;
  float* NEI   = ws + F_NEI;
  int*   DEG   = (int*)(ws + F_DEG);
  int*   FLAG  = (int*)(ws + F_FLAG);
  int*   MSK   = (int*)(ws + F_MSK);
  float* WXW   = ws + F_WXW;
  float* WXB   = ws + F_WXB;
  float* WPROJ = ws + F_WPROJ;
  float* REG   = ws + F_REGION;
  // enc/ctx phase
  __hip_bfloat16* GI16  = (__hip_bfloat16*)REG;             // 32768x768 bf16
  float* OUT   = REG + 13631488;                            // 8.39M fp32
  // TL phase
  __hip_bfloat16* XWALL16 = (__hip_bfloat16*)REG;           // 32768x1024 bf16
  float* HARR  = REG + 17000000;                            // 8.39M
  float* CARR  = REG + 25500000;                            // 8.39M
  __hip_bfloat16* HU16 = (__hip_bfloat16*)(REG + 34000000); // 64x512x1024 bf16
  float* XN    = REG + 51000000;                            // 8.39M
  // fa phase
  __hip_bfloat16* GIFA16 = (__hip_bfloat16*)REG;            // 2560x768 bf16
  float* OUTFA = REG + 1966080;

  auto gemm = [&](const float* A, const int* ridx, int rstride, const float* W,
                  const float* bias, float* C, int R, int K, int J, int relu,
                  int obf) {
    dim3 g((R / 128) * (J / 128));
    k_gemm128<<<g, 256, 0, stream>>>(A, ridx, rstride, W, bias, C, R, K, J, relu, obf);
  };

  // ---- prep ----
  k_build_wx<<<1024, 256, 0, stream>>>(tl_wiou, tl_wf, tl_biou, tl_bf, WXW, WXB);
  k_build_wproj<<<1024, 256, 0, stream>>>(tl_uiou, tl_uf, WPROJ);
  k_zero_misc<<<512, 256, 0, stream>>>(NEI, DEG, FLAG);
  k_mask_detect<<<128, 256, 0, stream>>>((const unsigned*)ast_mask_raw, FLAG);
  k_mask_convert<<<512, 256, 0, stream>>>(ast_mask_raw, FLAG, MSK);

  // ---- 3 sequence encoders: slots 0 (stmt), 2 (varn), 3 (vart) ----
  const int slot_of[3] = {0, 2, 3};
  for (int e = 0; e < 3; ++e) {
    gemm(seq_emb + (size_t)e * 50000 * 256, seq_tokens + (size_t)e * 32768, 256,
         seq_wih + (size_t)e * 768 * 256, seq_bih + (size_t)e * 768, (float*)GI16,
         32768, 256, 768, 0, 1);
    k_gru3<<<dim3(128, 2), 512, 0, stream>>>(GI16, seq_whh + (size_t)e * 2 * 384 * 128,
                                             seq_bhh + (size_t)e * 768, OUT, 64);
    k_attn_pool<<<512, 256, 0, stream>>>(OUT, 64 * 256, 256, OUT, 64 * 256, 256,
                                         seq_pw + e * 256, seq_pb + e,
                                         FEATS + slot_of[e] * 256, 1280, 64);
  }

  // ---- ctx encoder (needs stmt slot0): slot 4 ----
  gemm(FEATS, ctx_nei, 1280, ctx_wih, ctx_bih, (float*)GI16, 4096, 256, 768, 0, 1);
  k_gru3<<<dim3(128, 2), 512, 0, stream>>>(GI16, ctx_whh, ctx_bhh, OUT, 8);
  k_attn_pool<<<512, 256, 0, stream>>>(OUT, 8 * 256, 256, OUT, 8 * 256, 256,
                                       ctx_pw, ctx_pb, FEATS + 4 * 256, 1280, 8);

  // ---- AST TreeLSTM: slot 1 ----
  k_xn<<<32768, 256, 0, stream>>>(ast_label_tab, ast_tok_tab, ast_label_ids,
                                  ast_tok_ids, XN);
  gemm(XN, nullptr, 256, WXW, WXB, (float*)XWALL16, 32768, 256, 1024, 0, 1);
  for (int m = 0; m < 64; ++m) {
    k_tl_combine4<<<512, 256, 0, stream>>>(HU16, XWALL16, ast_children, MSK,
                                           HARR, CARR, m);
    if (m < 63)
      k_tl_proj<<<128, 256, 0, stream>>>(HARR, WPROJ, HU16, m);
  }
  k_attn_pool<<<512, 256, 0, stream>>>(HARR, 256, 512 * 256, HARR, 256, 512 * 256,
                                       ast_pw, ast_pb, FEATS + 1 * 256, 1280, 64);

  // ---- feature-attention biGRU over the 5 slots -> x ----
  gemm(FEATS, nullptr, 256, fa_wih, fa_bih, (float*)GIFA16, 2560, 256, 768, 0, 1);
  k_gru3<<<dim3(128, 2), 512, 0, stream>>>(GIFA16, fa_whh, fa_bhh, OUTFA, 5);
  k_attn_pool<<<512, 256, 0, stream>>>(OUTFA, 5 * 256, 256, FEATS, 1280, 256,
                                       fa_aw, fa_ab, X, 256, 5);

  // ---- graph section ----
  k_edge_deg<<<(E + 255) / 256, 256, 0, stream>>>(edges, DEG, E);
  k_nei<<<E, 256, 0, stream>>>(edges, X, NEI);
  k_xcat<<<512, 256, 0, stream>>>(X, NEI, DEG, XCAT);
  gemm(XCAT, nullptr, 512, comb_w, comb_b, X2, 512, 512, 256, 1, 0);
  gemm(X2, nullptr, 256, g1_w, g1_b, Y, 512, 256, 256, 0, 0);
  k_spmm_self<<<512, 256, 0, stream>>>(Y, DEG, H1);
  k_spmm_edge<<<E, 256, 0, stream>>>(Y, DEG, edges, H1);
  k_relu_inplace<<<512, 256, 0, stream>>>(H1);
  gemm(H1, nullptr, 256, g2_w, g2_b, Y, 512, 256, 256, 0, 0);
  k_spmm_self<<<512, 256, 0, stream>>>(Y, DEG, H2);
  k_spmm_edge<<<E, 256, 0, stream>>>(Y, DEG, edges, H2);
  k_relu_inplace<<<512, 256, 0, stream>>>(H2);
  k_final<<<1, 256, 0, stream>>>(H2, cls_w1, cls_b1, cls_w2, cls_b2, outp);
}